// Round 2
// baseline (289.454 us; speedup 1.0000x reference)
//
#include <hip/hip_runtime.h>

#define NB 4
#define NT 2048
#define NE 512
#define NH 8
#define ND 64
#define BH (NB*NH)

typedef __attribute__((ext_vector_type(8))) short short8;
typedef __attribute__((ext_vector_type(4))) short short4v;
typedef __attribute__((ext_vector_type(4))) float f32x4;

typedef const __attribute__((address_space(3))) short* lds_sp;

__device__ __forceinline__ f32x4 mfma16(short8 a, short8 b, f32x4 c){
  return __builtin_amdgcn_mfma_f32_16x16x32_bf16(a, b, c, 0, 0, 0);
}
__device__ __forceinline__ short f2b(float f){
  union { float f; unsigned u; } v; v.f = f;
  unsigned r = v.u + 0x7FFFu + ((v.u >> 16) & 1u);
  return (short)(r >> 16);
}
__device__ __forceinline__ float b2f(short s){
  union { unsigned u; float f; } v; v.u = ((unsigned)(unsigned short)s) << 16; return v.f;
}
__device__ __forceinline__ void gld16(const void* g, void* l){
  __builtin_amdgcn_global_load_lds((const __attribute__((address_space(1))) void*)g,
                                   (__attribute__((address_space(3))) void*)l, 16, 0, 0);
}
__device__ __forceinline__ short4v trr(lds_sp p, int imm){
  short4v r;
  asm volatile("ds_read_b64_tr_b16 %0, %1 offset:%2" : "=v"(r) : "v"(p), "i"(imm));
  return r;
}

// ---------------- pack x (fp32 -> bf16) ----------------
__global__ __launch_bounds__(256) void pack_x_k(const float* __restrict__ x, short* __restrict__ xb){
  int i = blockIdx.x*256 + threadIdx.x;
  f32x4 a = ((const f32x4*)x)[2*i];
  f32x4 b = ((const f32x4*)x)[2*i+1];
  short8 o;
  o[0]=f2b(a[0]); o[1]=f2b(a[1]); o[2]=f2b(a[2]); o[3]=f2b(a[3]);
  o[4]=f2b(b[0]); o[5]=f2b(b[1]); o[6]=f2b(b[2]); o[7]=f2b(b[3]);
  ((short8*)xb)[i] = o;
}

// ---------------- pack W transposed (fp32 [e][j] -> bf16 [j][e]) ----------------
__global__ __launch_bounds__(256) void pack_wt_k(const float* __restrict__ Wq, const float* __restrict__ Wk,
                                                 const float* __restrict__ Wv, const float* __restrict__ Wo,
                                                 short* __restrict__ Wt){
  const float* W = blockIdx.z==0?Wq: blockIdx.z==1?Wk: blockIdx.z==2?Wv:Wo;
  short* out = Wt + (size_t)blockIdx.z*NE*NE;
  __shared__ float t[32][33];
  int tx = threadIdx.x & 31, ty = threadIdx.x >> 5;
  int j0 = blockIdx.x*32, e0 = blockIdx.y*32;
#pragma unroll
  for (int r = 0; r < 4; ++r)
    t[ty*4+r][tx] = W[(size_t)(e0+ty*4+r)*NE + j0+tx];
  __syncthreads();
#pragma unroll
  for (int r = 0; r < 4; ++r)
    out[(size_t)(j0+ty*4+r)*NE + e0+tx] = f2b(t[tx][ty*4+r]);
}

// ---------------- QKV projection GEMM ----------------
__global__ __launch_bounds__(256) void gemm_qkv_k(const short* __restrict__ xb, const short* __restrict__ Wt,
                                                  const float* __restrict__ bq, const float* __restrict__ bk,
                                                  const float* __restrict__ bv,
                                                  short* __restrict__ Q, short* __restrict__ K, short* __restrict__ V){
  int z = blockIdx.z;
  const short* Bm = Wt + (size_t)z*NE*NE;
  const float* bias = z==0?bq: z==1?bk:bv;
  short* out = z==0?Q: z==1?K:V;
  float scale = (z==0) ? 0.125f : 1.0f;   // fold 1/sqrt(D) into Q

  __shared__ short As[128*32];
  __shared__ short Bs[128*32];
  int tid = threadIdx.x, lane = tid & 63, wid = tid >> 6;
  int m0 = blockIdx.y*128, n0 = blockIdx.x*128;
  int wm = wid >> 1, wn = wid & 1;
  int sr = lane >> 2, sg = lane & 3;
  int fr = lane & 15, fg = lane >> 4;

  f32x4 acc[4][4] = {};

  for (int kt = 0; kt < 16; ++kt){
    int k0 = kt*32;
    {
      int ii0 = wid*2, ii1 = wid*2+1;
      int r0 = ii0*16 + sr, r1 = ii1*16 + sr;
      gld16(xb + (size_t)(m0 + r0)*NE + k0 + ((sg ^ (r0&3))<<3), (short*)As + ii0*512);
      gld16(xb + (size_t)(m0 + r1)*NE + k0 + ((sg ^ (r1&3))<<3), (short*)As + ii1*512);
      gld16(Bm + (size_t)(n0 + r0)*NE + k0 + ((sg ^ (r0&3))<<3), (short*)Bs + ii0*512);
      gld16(Bm + (size_t)(n0 + r1)*NE + k0 + ((sg ^ (r1&3))<<3), (short*)Bs + ii1*512);
    }
    __syncthreads();
    short8 af[4], bf[4];
#pragma unroll
    for (int m = 0; m < 4; ++m){
      int row = wm*64 + m*16 + fr;
      af[m] = *(const short8*)&As[row*32 + ((fg ^ (row&3))<<3)];
    }
#pragma unroll
    for (int n = 0; n < 4; ++n){
      int row = wn*64 + n*16 + fr;
      bf[n] = *(const short8*)&Bs[row*32 + ((fg ^ (row&3))<<3)];
    }
#pragma unroll
    for (int m = 0; m < 4; ++m)
#pragma unroll
      for (int n = 0; n < 4; ++n)
        acc[m][n] = mfma16(af[m], bf[n], acc[m][n]);
    __syncthreads();
  }
#pragma unroll
  for (int m = 0; m < 4; ++m)
#pragma unroll
    for (int n = 0; n < 4; ++n)
#pragma unroll
      for (int i = 0; i < 4; ++i){
        int row = m0 + wm*64 + m*16 + fg*4 + i;
        int col = n0 + wn*64 + n*16 + fr;
        float v = (acc[m][n][i] + bias[col]) * scale;
        int b = row >> 11, t = row & (NT-1), h = col >> 6, d = col & 63;
        out[(((size_t)(b*NH + h)*NT + t)<<6) + d] = f2b(v);
      }
}

// ---------------- pass 1: l_k = sum_q exp(S[q][k]) — no LDS, no barriers ----------------
__global__ __launch_bounds__(512, 4) void attn_l_k(const short* __restrict__ Q, const short* __restrict__ K,
                                                   float* __restrict__ lbuf){
  int bh = blockIdx.y;
  const short* Qh = Q + (size_t)bh*NT*ND;
  const short* Kh = K + (size_t)bh*NT*ND;
  int kb = blockIdx.x*128;
  int tid = threadIdx.x, lane = tid&63, wid = tid>>6;
  int fr = lane&15, fg = lane>>4;
  int krow = kb + wid*16;

  short8 ak[2];
#pragma unroll
  for (int dh = 0; dh < 2; ++dh)
    ak[dh] = *(const short8*)&Kh[(size_t)(krow + fr)*ND + dh*32 + fg*8];

  float rsum[4] = {0.f,0.f,0.f,0.f};
  for (int qt = 0; qt < 32; ++qt){
#pragma unroll
    for (int qf = 0; qf < 4; ++qf){
      short8 b0 = *(const short8*)&Qh[(size_t)(qt*64 + qf*16 + fr)*ND + fg*8];
      short8 b1 = *(const short8*)&Qh[(size_t)(qt*64 + qf*16 + fr)*ND + 32 + fg*8];
      f32x4 c = {};
      c = mfma16(ak[0], b0, c);
      c = mfma16(ak[1], b1, c);
#pragma unroll
      for (int i = 0; i < 4; ++i)
        rsum[i] += __expf(c[i]);
    }
  }
#pragma unroll
  for (int i = 0; i < 4; ++i){
    float v = rsum[i];
    v += __shfl_xor(v, 1); v += __shfl_xor(v, 2);
    v += __shfl_xor(v, 4); v += __shfl_xor(v, 8);
    if (fr == 0) lbuf[(size_t)bh*NT + krow + fg*4 + i] = v;
  }
}

// ---------------- fold 1/l into V: Vp = V / l_k ----------------
__global__ __launch_bounds__(256) void scale_v_k(const short* __restrict__ V, const float* __restrict__ lbuf,
                                                 short* __restrict__ Vp){
  int idx = blockIdx.x*256 + threadIdx.x;
  int R = idx >> 3, d0 = (idx&7)*8;
  float inv = 1.0f / lbuf[R];
  short8 v = *(const short8*)&V[((size_t)R<<6) + d0];
  short8 o;
#pragma unroll
  for (int j = 0; j < 8; ++j) o[j] = f2b(b2f(v[j]) * inv);
  *(short8*)&Vp[((size_t)R<<6) + d0] = o;
}

// ---------------- pass 2: P = exp(S) in-register, PV via tr-reads, scrambled write ----------------
// V LDS layout: [16][16] row-major tiles T[kb][n] (kb=k/16, n=d/16) at (kb*4+n)*256 shorts.
// tr-read at tile base + lane*8B gives lane(fr,fg): V[kb*16+4*fg+j][n*16+fr] — matches the
// k-permutation of the swapped-S^T A-fragment (jj<4: k=32c+4fg+jj; jj>=4: k=32c+16+4fg+jj-4).
__global__ __launch_bounds__(512, 4) void attn_out_k(const short* __restrict__ Q, const short* __restrict__ K,
                                                     const short* __restrict__ Vp,
                                                     short* __restrict__ out2){
  int bh = blockIdx.y, b = bh >> 3, h = bh & 7;
  const short* Qh = Q + (size_t)bh*NT*ND;
  const short* Kh = K + (size_t)bh*NT*ND;
  const short* Vh = Vp + (size_t)bh*NT*ND;
  int q0 = blockIdx.x*128;
  __shared__ short Vs[2][4096];
  int tid = threadIdx.x, lane = tid&63, wid = tid>>6;
  int fr = lane&15, fg = lane>>4;
  int qw = q0 + wid*16;

  // Q fragments hoisted to registers (B-operand of swapped QK^T)
  short8 qreg[2];
#pragma unroll
  for (int dh = 0; dh < 2; ++dh)
    qreg[dh] = *(const short8*)&Qh[(size_t)(qw + fr)*ND + dh*32 + fg*8];

  // V staging map: instr=wid, linear p = wid*512 + lane*8 shorts
  //  -> tile t=wid*2+(lane>>5), row r=(lane&31)>>1, col0=(lane&1)*8; t=(kb,n)=(t>>2,t&3)
  int vt = wid*2 + (lane>>5);
  int vkb = vt>>2, vn = vt&3;
  int vr = (lane&31)>>1, vc0 = (lane&1)*8;
  const short* vsrc0 = Vh + (size_t)(vkb*16 + vr)*ND + vn*16 + vc0;

  gld16(vsrc0, (short*)Vs[0] + wid*512);   // prologue: stage kt=0

  f32x4 oacc[4] = {};

  for (int kt = 0; kt < 32; ++kt){
    int cur = kt & 1;
    __syncthreads();   // buf[cur] staged; buf[cur^1] free

    // swapped QK^T: K rows from global (L1/L2-hot), 8 MFMA
    f32x4 s[4];
#pragma unroll
    for (int rf = 0; rf < 4; ++rf){
      const short* kp = &Kh[(size_t)(kt*64 + rf*16 + fr)*ND + fg*8];
      short8 ak0 = *(const short8*)kp;
      short8 ak1 = *(const short8*)(kp + 32);
      f32x4 c = {};
      c = mfma16(ak0, qreg[0], c);
      c = mfma16(ak1, qreg[1], c);
      s[rf] = c;
    }

    // prefetch next V tile AFTER K loads consumed (keeps vmcnt waits off the prefetch)
    if (kt < 31)
      gld16(vsrc0 + (size_t)(kt+1)*64*ND, (short*)Vs[cur^1] + wid*512);

    // P = exp(S) packed directly into PV A-fragments (pi-permuted k order)
    short8 pa[2];
#pragma unroll
    for (int c = 0; c < 2; ++c){
#pragma unroll
      for (int i = 0; i < 4; ++i){
        pa[c][i]   = f2b(__expf(s[2*c][i]));
        pa[c][4+i] = f2b(__expf(s[2*c+1][i]));
      }
    }

    // PV via hardware transpose reads of V subtiles
    lds_sp vbase = (lds_sp)(const short*)((const short*)Vs[cur] + lane*4); // byte addr = base + lane*8
#pragma unroll
    for (int c = 0; c < 2; ++c){
      short4v t0[4], t1[4];
#pragma unroll
      for (int n = 0; n < 4; ++n){
        t0[n] = trr(vbase, ((2*c  )*4 + n)*512);
        t1[n] = trr(vbase, ((2*c+1)*4 + n)*512);
      }
      asm volatile("s_waitcnt lgkmcnt(0)");
      __builtin_amdgcn_sched_barrier(0);
#pragma unroll
      for (int n = 0; n < 4; ++n){
        short8 vb;
#pragma unroll
        for (int j = 0; j < 4; ++j){ vb[j] = t0[n][j]; vb[4+j] = t1[n][j]; }
        oacc[n] = mfma16(pa[c], vb, oacc[n]);
      }
    }
  }

  // scrambled reshape write: (B,H,T,D) -> (B, T', H*D), r=h*256+t/8, e=64*(t%8)+d
#pragma unroll
  for (int n = 0; n < 4; ++n)
#pragma unroll
    for (int i = 0; i < 4; ++i){
      int t = qw + fg*4 + i;
      int d = n*16 + fr;
      int r = h*256 + (t>>3);
      int e = ((t&7)<<6) + d;
      out2[((size_t)(b*NT + r)<<9) + e] = f2b(oacc[n][i]);
    }
}

// ---------------- output projection: out2 @ Wo + bo -> fp32 ----------------
__global__ __launch_bounds__(256) void gemm_out_k(const short* __restrict__ A, const short* __restrict__ Bm,
                                                  const float* __restrict__ bo, float* __restrict__ out){
  __shared__ short As[128*32];
  __shared__ short Bs[128*32];
  int tid = threadIdx.x, lane = tid & 63, wid = tid >> 6;
  int m0 = blockIdx.y*128, n0 = blockIdx.x*128;
  int wm = wid >> 1, wn = wid & 1;
  int sr = lane >> 2, sg = lane & 3;
  int fr = lane & 15, fg = lane >> 4;

  f32x4 acc[4][4] = {};

  for (int kt = 0; kt < 16; ++kt){
    int k0 = kt*32;
    {
      int ii0 = wid*2, ii1 = wid*2+1;
      int r0 = ii0*16 + sr, r1 = ii1*16 + sr;
      gld16(A  + (size_t)(m0 + r0)*NE + k0 + ((sg ^ (r0&3))<<3), (short*)As + ii0*512);
      gld16(A  + (size_t)(m0 + r1)*NE + k0 + ((sg ^ (r1&3))<<3), (short*)As + ii1*512);
      gld16(Bm + (size_t)(n0 + r0)*NE + k0 + ((sg ^ (r0&3))<<3), (short*)Bs + ii0*512);
      gld16(Bm + (size_t)(n0 + r1)*NE + k0 + ((sg ^ (r1&3))<<3), (short*)Bs + ii1*512);
    }
    __syncthreads();
    short8 af[4], bf[4];
#pragma unroll
    for (int m = 0; m < 4; ++m){
      int row = wm*64 + m*16 + fr;
      af[m] = *(const short8*)&As[row*32 + ((fg ^ (row&3))<<3)];
    }
#pragma unroll
    for (int n = 0; n < 4; ++n){
      int row = wn*64 + n*16 + fr;
      bf[n] = *(const short8*)&Bs[row*32 + ((fg ^ (row&3))<<3)];
    }
#pragma unroll
    for (int m = 0; m < 4; ++m)
#pragma unroll
      for (int n = 0; n < 4; ++n)
        acc[m][n] = mfma16(af[m], bf[n], acc[m][n]);
    __syncthreads();
  }
#pragma unroll
  for (int m = 0; m < 4; ++m)
#pragma unroll
    for (int n = 0; n < 4; ++n)
#pragma unroll
      for (int i = 0; i < 4; ++i){
        int row = m0 + wm*64 + m*16 + fg*4 + i;
        int col = n0 + wn*64 + n*16 + fr;
        out[(size_t)row*NE + col] = acc[m][n][i] + bo[col];
      }
}

extern "C" void kernel_launch(void* const* d_in, const int* in_sizes, int n_in,
                              void* d_out, int out_size, void* d_ws, size_t ws_size,
                              hipStream_t stream){
  const float* x  = (const float*)d_in[0];
  const float* Wq = (const float*)d_in[1];
  const float* bq = (const float*)d_in[2];
  const float* Wk = (const float*)d_in[3];
  const float* bk = (const float*)d_in[4];
  const float* Wv = (const float*)d_in[5];
  const float* bv = (const float*)d_in[6];
  const float* Wo = (const float*)d_in[7];
  const float* bo = (const float*)d_in[8];
  float* out = (float*)d_out;

  char* ws = (char*)d_ws;
  size_t off = 0;
  auto alloc = [&](size_t bytes){ void* p = ws + off; off = (off + bytes + 255) & ~(size_t)255; return p; };
  short* xb    = (short*)alloc((size_t)NB*NT*NE*2);
  short* Wt    = (short*)alloc((size_t)4*NE*NE*2);
  short* Qb    = (short*)alloc((size_t)NB*NT*NE*2);
  short* Kb    = (short*)alloc((size_t)NB*NT*NE*2);
  short* Vb    = (short*)alloc((size_t)NB*NT*NE*2);
  short* Vp    = (short*)alloc((size_t)NB*NT*NE*2);
  float* lbuf  = (float*)alloc((size_t)BH*NT*sizeof(float));
  short* out2  = (short*)alloc((size_t)NB*NT*NE*2);
  (void)ws_size; (void)in_sizes; (void)n_in; (void)out_size;

  pack_x_k<<<dim3((NB*NT*NE/8)/256), dim3(256), 0, stream>>>(x, xb);
  pack_wt_k<<<dim3(NE/32, NE/32, 4), dim3(256), 0, stream>>>(Wq, Wk, Wv, Wo, Wt);
  gemm_qkv_k<<<dim3(NE/128, (NB*NT)/128, 3), dim3(256), 0, stream>>>(xb, Wt, bq, bk, bv, Qb, Kb, Vb);
  attn_l_k<<<dim3(NT/128, BH), dim3(512), 0, stream>>>(Qb, Kb, lbuf);
  scale_v_k<<<dim3((NB*NT*NE/8)/256), dim3(256), 0, stream>>>(Vb, lbuf, Vp);
  attn_out_k<<<dim3(NT/128, BH), dim3(512), 0, stream>>>(Qb, Kb, Vp, out2);
  gemm_out_k<<<dim3(NE/128, (NB*NT)/128), dim3(256), 0, stream>>>(out2, Wt + (size_t)3*NE*NE, bo, out);
}